// Round 6
// baseline (81.618 us; speedup 1.0000x reference)
//
#include <hip/hip_runtime.h>
#include <hip/hip_bf16.h>

#define NROWS 8192
#define DIM 64
#define NT 64                     // 64x64 grid of 128x128 tiles
#define NTRI (NT * (NT + 1) / 2)  // 2080 upper-triangle tiles

typedef __attribute__((ext_vector_type(8))) short short8;   // 8 bf16 = 4 VGPRs
typedef __attribute__((ext_vector_type(4))) float f32x4;    // MFMA 16x16 accumulator

static constexpr float LOG2E = 1.4426950408889634f;

#if defined(__has_builtin) && __has_builtin(__builtin_amdgcn_exp2f)
#define EXP2F(x) __builtin_amdgcn_exp2f(x)
#else
#define EXP2F(x) exp2f(x)
#endif

// Fully fused main kernel: NO separate prep pass. Each block stages its own
// 128 A-rows + 128 B-rows directly from X (f32, L2-resident): multiply by
// sqrt(params), convert to bf16 into panelized LDS, and compute the row
// norms (Lsq) in LDS using the BIT-IDENTICAL lane mapping + xor-shuffle
// order the old prep_kernel used (same rounding -> same final scalar).
// Rationale: rounds 3-5 proved kta-internal changes are neutral (74.3/75.4/
// 74.9), while rounds 1-2 showed the serial chain outside kta (prep + launch
// gaps) is ~15 us. This removes the prep dispatch + one gap + the 1 MB Xp
// global round-trip. Redundant per-block conversion (~300 VALU instrs/thread)
// overlaps across the ~3 resident blocks/CU; extra X reads come from L2.
// Panel layout within LDS (identical to the old global Xp, per 128-row tile):
//   unit = (row/16)*128 + chunk*16 + (row%16), unit = 16 B (8 bf16).
// NO fused finalize (rounds 1-2: per-block device fence+atomic = +26 us).
__global__ __launch_bounds__(256, 3) void kta_main(const float* __restrict__ X,
                                                   const float* __restrict__ params,
                                                   const float* __restrict__ t,
                                                   float2* __restrict__ partial) {
    int k = blockIdx.x;
    // decode triangular index: row it has tiles jt = it..NT-1; C(i)=i*(129-i)/2
    int it = (int)((129.0f - sqrtf(16641.0f - 8.0f * (float)k)) * 0.5f);
    if (it > NT - 1) it = NT - 1;
    while ((it * (129 - it)) / 2 > k) --it;
    while (((it + 1) * (128 - it)) / 2 <= k) ++it;
    int jt = it + (k - (it * (129 - it)) / 2);

    int tid  = threadIdx.x;
    int wave = tid >> 6, lane = tid & 63;
    int quad = lane >> 4, l16 = lane & 15;
    int r8 = lane >> 3, ch = lane & 7;    // staging: 8 rows x 8 chunks per wave

    __shared__ short8 As[1024];   // 8 panels x 128 units = 16 KB
    __shared__ short8 Bs[1024];   // 16 KB
    __shared__ float  LA[128];    // LOG2E * bf16-rounded row norms (A side)
    __shared__ float  LB[128];

    // sqrt(params) for this lane's 8-wide chunk (256 B array, L2/L1-hot).
    float4 p0 = *(const float4*)(params + ch * 8);
    float4 p1 = *(const float4*)(params + ch * 8 + 4);
    float sp[8];
    sp[0] = sqrtf(p0.x); sp[1] = sqrtf(p0.y); sp[2] = sqrtf(p0.z); sp[3] = sqrtf(p0.w);
    sp[4] = sqrtf(p1.x); sp[5] = sqrtf(p1.y); sp[6] = sqrtf(p1.z); sp[7] = sqrtf(p1.w);

    // Stage one 128-row side: 4 passes x (4 waves x 8 rows). Identical
    // arithmetic + reduction order to the old prep_kernel -> identical bits.
    auto stage = [&](int rowbase, short8* __restrict__ S, float* __restrict__ L) {
        #pragma unroll
        for (int pass = 0; pass < 4; ++pass) {
            int rl = pass * 32 + wave * 8 + r8;          // local row 0..127
            const float* xr = X + (size_t)(rowbase + rl) * DIM + ch * 8;
            float4 x0 = *(const float4*)xr;
            float4 x1 = *(const float4*)(xr + 4);
            float v[8];
            v[0] = x0.x * sp[0]; v[1] = x0.y * sp[1];
            v[2] = x0.z * sp[2]; v[3] = x0.w * sp[3];
            v[4] = x1.x * sp[4]; v[5] = x1.y * sp[5];
            v[6] = x1.z * sp[6]; v[7] = x1.w * sp[7];
            short8 h;
            float s = 0.f;
            #pragma unroll
            for (int i = 0; i < 8; ++i) {
                __hip_bfloat16 b = __float2bfloat16(v[i]);
                union { __hip_bfloat16 bb; short ss; } u; u.bb = b;
                h[i] = u.ss;
                float bf = __bfloat162float(b);   // rounded, consistent with MFMA dot
                s = fmaf(bf, bf, s);
            }
            S[(rl >> 4) * 128 + ch * 16 + (rl & 15)] = h;
            // sum over the 8 chunk-lanes of this row (xor over lane bits 0..2)
            #pragma unroll
            for (int m = 1; m < 8; m <<= 1) s += __shfl_xor(s, m, 64);
            if (ch == 0) L[rl] = LOG2E * s;
        }
    };

    bool diag = (it == jt);
    stage(it * 128, As, LA);
    if (!diag) stage(jt * 128, Bs, LB);
    const short8* Bsel = diag ? As : Bs;
    const float*  LBsl = diag ? LA : LB;

    int rbase = it * 128 + (wave >> 1) * 64;
    int cbase = jt * 128 + (wave & 1) * 64;

    // target-vector operands from global (32 KB array, L2-hot): issue before
    // the barrier so their latency hides under the staging drain.
    float tR[4][4];
    #pragma unroll
    for (int rt = 0; rt < 4; ++rt)
        #pragma unroll
        for (int r = 0; r < 4; ++r)
            tR[rt][r] = t[rbase + rt * 16 + quad * 4 + r];
    float tC[4];
    #pragma unroll
    for (int ct = 0; ct < 4; ++ct)
        tC[ct] = t[cbase + ct * 16 + l16];

    __syncthreads();

    int lpA = (wave >> 1) * 4;   // local A panel base for this wave
    int lpB = (wave & 1) * 4;

    // Norm operands from LDS (bit-identical to old global Lsq values).
    float LsqR[4][4];
    #pragma unroll
    for (int rt = 0; rt < 4; ++rt)
        #pragma unroll
        for (int r = 0; r < 4; ++r)
            LsqR[rt][r] = LA[(wave >> 1) * 64 + rt * 16 + quad * 4 + r];
    float LsqC[4];
    #pragma unroll
    for (int ct = 0; ct < 4; ++ct)
        LsqC[ct] = LBsl[(wave & 1) * 64 + ct * 16 + l16];

    // B-fragments fully in regs (32 VGPR), reused by all 4 rt iterations.
    short8 bfr[4][2];
    #pragma unroll
    for (int ct = 0; ct < 4; ++ct)
        #pragma unroll
        for (int kc = 0; kc < 2; ++kc)
            bfr[ct][kc] = Bsel[(lpB + ct) * 128 + (kc * 4 + quad) * 16 + l16];

    bool diagwave = diag && ((wave >> 1) == (wave & 1));
    float s1 = 0.f, s2a = 0.f, s2b = 0.f;

    // Per-rt streaming: 2 ds_reads (A-frags) -> 8 MFMAs -> fused epilogue.
    // DIAG is a call-site literal; non-diag waves carry zero compare cost.
    auto body = [&](int DIAG) {
        #pragma unroll
        for (int rt = 0; rt < 4; ++rt) {
            short8 a0 = As[(lpA + rt) * 128 + quad * 16 + l16];
            short8 a1 = As[(lpA + rt) * 128 + (4 + quad) * 16 + l16];
            f32x4 cc[4];
            #pragma unroll
            for (int ct = 0; ct < 4; ++ct) {
                cc[ct] = (f32x4){0.f, 0.f, 0.f, 0.f};
                cc[ct] = __builtin_amdgcn_mfma_f32_16x16x32_bf16(a0, bfr[ct][0], cc[ct], 0, 0, 0);
                cc[ct] = __builtin_amdgcn_mfma_f32_16x16x32_bf16(a1, bfr[ct][1], cc[ct], 0, 0, 0);
            }
            // Epilogue. C/D layout: col = lane&15, row = quad*4 + reg.
            #pragma unroll
            for (int r = 0; r < 4; ++r) {
                float nr = LsqR[rt][r];
                float s1row = 0.f;
                #pragma unroll
                for (int ct = 0; ct < 4; ++ct) {
                    float dot = cc[ct][r];
                    // off-diag d2 >= ~15 for this data: no clamp needed;
                    // diagonal (the only d2~0 entries) pinned to 1 below.
                    float K = EXP2F(fmaf(dot, 2.0f * LOG2E, -(nr + LsqC[ct])));
                    if (DIAG && (rt == ct) && ((quad * 4 + r) == l16))
                        K = 1.0f;
                    s1row = fmaf(K, tC[ct], s1row);
                    if (ct & 2) s2b = fmaf(K, K, s2b);
                    else        s2a = fmaf(K, K, s2a);
                }
                s1 = fmaf(s1row, tR[rt][r], s1);
            }
        }
    };
    if (diagwave) body(1); else body(0);

    float s2 = s2a + s2b;
    float w = diag ? 1.0f : 2.0f;
    s1 *= w; s2 *= w;
    #pragma unroll
    for (int m = 32; m > 0; m >>= 1) {
        s1 += __shfl_xor(s1, m, 64);
        s2 += __shfl_xor(s2, m, 64);
    }

    __shared__ float2 red[4];
    if (lane == 0) red[wave] = make_float2(s1, s2);
    __syncthreads();
    if (tid == 0) {
        float2 a = red[0], b = red[1], cc = red[2], d = red[3];
        partial[k] = make_float2(a.x + b.x + cc.x + d.x, a.y + b.y + cc.y + d.y);
    }
}

// Single-block reduction of per-block partials (2080 float2 = 16.6 KB).
__global__ __launch_bounds__(256) void finalize_kernel(const float2* __restrict__ partial,
                                                       float* __restrict__ out) {
    float s1 = 0.f, s2 = 0.f;
    for (int i = threadIdx.x; i < NTRI; i += 256) {
        float2 p = partial[i];
        s1 += p.x;
        s2 += p.y;
    }
    #pragma unroll
    for (int m = 32; m > 0; m >>= 1) {
        s1 += __shfl_xor(s1, m, 64);
        s2 += __shfl_xor(s2, m, 64);
    }
    __shared__ float r1[4], r2[4];
    int wave = threadIdx.x >> 6, lane = threadIdx.x & 63;
    if (lane == 0) { r1[wave] = s1; r2[wave] = s2; }
    __syncthreads();
    if (threadIdx.x == 0) {
        float a = r1[0] + r1[1] + r1[2] + r1[3];
        float b = r2[0] + r2[1] + r2[2] + r2[3];
        out[0] = -a / ((float)NROWS * sqrtf(b));
    }
}

extern "C" void kernel_launch(void* const* d_in, const int* in_sizes, int n_in,
                              void* d_out, int out_size, void* d_ws, size_t ws_size,
                              hipStream_t stream) {
    const float* X      = (const float*)d_in[0];
    const float* target = (const float*)d_in[1];
    const float* params = (const float*)d_in[2];
    float* out = (float*)d_out;

    float* ws = (float*)d_ws;
    float2* partial = (float2*)ws;                 // 2080 float2 (16.6 KB)

    kta_main<<<NTRI, 256, 0, stream>>>(X, params, target, partial);
    finalize_kernel<<<1, 256, 0, stream>>>(partial, out);
}

// Round 7
// 76.213 us; speedup vs baseline: 1.0709x; 1.0709x over previous
//
#include <hip/hip_runtime.h>
#include <hip/hip_bf16.h>

#define NROWS 8192
#define DIM 64
#define NT 64                     // 64x64 grid of 128x128 tiles
#define NTRI (NT * (NT + 1) / 2)  // 2080 upper-triangle tiles

typedef __attribute__((ext_vector_type(8))) short short8;   // 8 bf16 = 4 VGPRs
typedef __attribute__((ext_vector_type(4))) float f32x4;    // MFMA 16x16 accumulator

static constexpr float LOG2E = 1.4426950408889634f;

#if defined(__has_builtin) && __has_builtin(__builtin_amdgcn_exp2f)
#define EXP2F(x) __builtin_amdgcn_exp2f(x)
#else
#define EXP2F(x) exp2f(x)
#endif

// Panelized bf16 layout: panel p = row/16 holds rows 16p..16p+15.
// Within a panel, 8 k-chunks (c = k/8), stored chunk-major in 16B units:
//   unit_index = p*128 + c*16 + (row%16)
// An MFMA A/B fragment load (lane l16 = row%16, quad = (k/8)%4) is then a
// fully-coalesced contiguous 1KB wave load — no cache-line splits.
//
// Xp/Lsq are written NONTEMPORAL: normal stores leave the lines dirty in the
// producing XCD's private L2 (each XCD ends up owning ~1/8 of Xp), and kta
// blocks on the other 7 XCDs then pay remote-dirty-line resolution (~700-900
// cyc) on every panel fragment load. nt stores stream past L2 so consumers
// get uniform clean L3 hits instead. (Rounds 3-5 showed occupancy/prefetch
// can't hide the stall; this attacks its latency at the source.)
__global__ __launch_bounds__(256) void prep_kernel(const float* __restrict__ X,
                                                   const float* __restrict__ params,
                                                   float* __restrict__ Lsq,
                                                   short* __restrict__ Xp) {
    int tid  = threadIdx.x;
    int wave = tid >> 6, lane = tid & 63;
    int r8 = lane >> 3, c = lane & 7;        // 8 rows x 8 chunks per wave
    int row = blockIdx.x * 32 + wave * 8 + r8;

    const float* xr = X + row * DIM + c * 8;
    float4 x0 = *(const float4*)xr;
    float4 x1 = *(const float4*)(xr + 4);
    float4 p0 = *(const float4*)(params + c * 8);
    float4 p1 = *(const float4*)(params + c * 8 + 4);

    float v[8];
    v[0] = x0.x * sqrtf(p0.x); v[1] = x0.y * sqrtf(p0.y);
    v[2] = x0.z * sqrtf(p0.z); v[3] = x0.w * sqrtf(p0.w);
    v[4] = x1.x * sqrtf(p1.x); v[5] = x1.y * sqrtf(p1.y);
    v[6] = x1.z * sqrtf(p1.z); v[7] = x1.w * sqrtf(p1.w);

    short8 h;
    float s = 0.f;
    #pragma unroll
    for (int i = 0; i < 8; ++i) {
        __hip_bfloat16 b = __float2bfloat16(v[i]);
        union { __hip_bfloat16 bb; short ss; } u; u.bb = b;
        h[i] = u.ss;
        float bf = __bfloat162float(b);   // rounded value, consistent with MFMA dot
        s += bf * bf;
    }

    int panel = row >> 4, pr = row & 15;
    __builtin_nontemporal_store(h, &((short8*)Xp)[panel * 128 + c * 16 + pr]);

    // sum s over the 8 chunk-lanes of this row (xor over lane bits 0..2)
    #pragma unroll
    for (int m = 1; m < 8; m <<= 1) s += __shfl_xor(s, m, 64);
    if (c == 0) __builtin_nontemporal_store(LOG2E * s, &Lsq[row]);
}

// Main: compact upper-triangle grid of 128x128 tiles; each of 4 waves computes
// a 64x64 subtile via 16x16x32 bf16 MFMA from the panelized layout, then a
// fused exp epilogue. All fragments + all 16 acc tiles live (max in-wave ILP);
// epilogue operands prefetched BEFORE the MFMA cluster so their L2 latency
// hides under the MFMAs. NO fused finalize: the per-block device-scope
// fence+atomic tail (rounds 1-2) doubled kta_main's time (23->49.5 us).
// NO fused prep: round 6 showed per-block re-conversion costs ~13 us against
// ~7 us of launch savings.
__global__ __launch_bounds__(256, 2) void kta_main(const short* __restrict__ Xp,
                                                   const float* __restrict__ Lsq,
                                                   const float* __restrict__ t,
                                                   float2* __restrict__ partial) {
    int k = blockIdx.x;
    // decode triangular index: row it has tiles jt = it..NT-1; C(i)=i*(129-i)/2
    int it = (int)((129.0f - sqrtf(16641.0f - 8.0f * (float)k)) * 0.5f);
    if (it > NT - 1) it = NT - 1;
    while ((it * (129 - it)) / 2 > k) --it;
    while (((it + 1) * (128 - it)) / 2 <= k) ++it;
    int jt = it + (k - (it * (129 - it)) / 2);

    int tid  = threadIdx.x;
    int wave = tid >> 6, lane = tid & 63;
    int quad = lane >> 4, l16 = lane & 15;
    int rbase = it * 128 + (wave >> 1) * 64;
    int cbase = jt * 128 + (wave & 1) * 64;

    // Coalesced fragment loads from panelized Xs.
    // A-operand (16x16x32 bf16): lane holds A[m=l16][k=quad*8+j]; B symmetric.
    const short8* Xpv = (const short8*)Xp;
    int pA0 = rbase >> 4, pB0 = cbase >> 4;
    short8 afr[4][2], bfr[4][2];
    #pragma unroll
    for (int rt = 0; rt < 4; ++rt) {
        #pragma unroll
        for (int kc = 0; kc < 2; ++kc) {
            afr[rt][kc] = Xpv[(pA0 + rt) * 128 + (kc * 4 + quad) * 16 + l16];
            bfr[rt][kc] = Xpv[(pB0 + rt) * 128 + (kc * 4 + quad) * 16 + l16];
        }
    }

    // Prefetch ALL epilogue operands before the MFMA cluster: their L2/L3
    // latency overlaps the 32-MFMA stream instead of stalling the epilogue.
    float LsqR[4][4], tR[4][4];
    #pragma unroll
    for (int rt = 0; rt < 4; ++rt)
        #pragma unroll
        for (int r = 0; r < 4; ++r) {
            int row = rbase + rt * 16 + quad * 4 + r;
            LsqR[rt][r] = Lsq[row];
            tR[rt][r]   = t[row];
        }
    float LsqC[4], tC[4];
    #pragma unroll
    for (int ct = 0; ct < 4; ++ct) {
        int col = cbase + ct * 16 + l16;
        LsqC[ct] = Lsq[col];
        tC[ct]   = t[col];
    }

    f32x4 c[4][4];
    #pragma unroll
    for (int rt = 0; rt < 4; ++rt)
        #pragma unroll
        for (int ct = 0; ct < 4; ++ct)
            c[rt][ct] = (f32x4){0.f, 0.f, 0.f, 0.f};

    #pragma unroll
    for (int rt = 0; rt < 4; ++rt)
        #pragma unroll
        for (int ct = 0; ct < 4; ++ct) {
            c[rt][ct] = __builtin_amdgcn_mfma_f32_16x16x32_bf16(afr[rt][0], bfr[ct][0], c[rt][ct], 0, 0, 0);
            c[rt][ct] = __builtin_amdgcn_mfma_f32_16x16x32_bf16(afr[rt][1], bfr[ct][1], c[rt][ct], 0, 0, 0);
        }

    bool diagwave = (it == jt) && ((wave >> 1) == (wave & 1));

    float s1 = 0.f, s2a = 0.f, s2b = 0.f;

    // DIAG is a call-site literal; clang inlines + const-folds both versions,
    // so non-diag waves (the vast majority) carry zero diagonal-compare cost.
    auto run = [&](int DIAG) {
        #pragma unroll
        for (int rt = 0; rt < 4; ++rt) {
            // Epilogue. C/D layout: col = lane&15, row = quad*4 + reg.
            #pragma unroll
            for (int r = 0; r < 4; ++r) {
                float nr = LsqR[rt][r];
                float s1row = 0.f;
                #pragma unroll
                for (int ct = 0; ct < 4; ++ct) {
                    float dot = c[rt][ct][r];
                    // off-diag d2 >= ~15 for this data: no clamp needed; diagonal
                    // (the only d2~0 entries) is pinned to 1 below.
                    float K = EXP2F(fmaf(dot, 2.0f * LOG2E, -(nr + LsqC[ct])));
                    // diag wave => rbase==cbase, so row==col iff rt==ct && quad*4+r==l16
                    if (DIAG && (rt == ct) && ((quad * 4 + r) == l16))
                        K = 1.0f;
                    s1row = fmaf(K, tC[ct], s1row);
                    if (ct & 2) s2b = fmaf(K, K, s2b);
                    else        s2a = fmaf(K, K, s2a);
                }
                s1 = fmaf(s1row, tR[rt][r], s1);
            }
        }
    };
    if (diagwave) run(1); else run(0);

    float s2 = s2a + s2b;
    float w = (it == jt) ? 1.0f : 2.0f;
    s1 *= w; s2 *= w;
    #pragma unroll
    for (int m = 32; m > 0; m >>= 1) {
        s1 += __shfl_xor(s1, m, 64);
        s2 += __shfl_xor(s2, m, 64);
    }

    __shared__ float2 red[4];
    if (lane == 0) red[wave] = make_float2(s1, s2);
    __syncthreads();
    if (tid == 0) {
        float2 a = red[0], b = red[1], cc = red[2], d = red[3];
        partial[k] = make_float2(a.x + b.x + cc.x + d.x, a.y + b.y + cc.y + d.y);
    }
}

// Single-block reduction of per-block partials (2080 float2 = 16.6 KB).
__global__ __launch_bounds__(256) void finalize_kernel(const float2* __restrict__ partial,
                                                       float* __restrict__ out) {
    float s1 = 0.f, s2 = 0.f;
    for (int i = threadIdx.x; i < NTRI; i += 256) {
        float2 p = partial[i];
        s1 += p.x;
        s2 += p.y;
    }
    #pragma unroll
    for (int m = 32; m > 0; m >>= 1) {
        s1 += __shfl_xor(s1, m, 64);
        s2 += __shfl_xor(s2, m, 64);
    }
    __shared__ float r1[4], r2[4];
    int wave = threadIdx.x >> 6, lane = threadIdx.x & 63;
    if (lane == 0) { r1[wave] = s1; r2[wave] = s2; }
    __syncthreads();
    if (threadIdx.x == 0) {
        float a = r1[0] + r1[1] + r1[2] + r1[3];
        float b = r2[0] + r2[1] + r2[2] + r2[3];
        out[0] = -a / ((float)NROWS * sqrtf(b));
    }
}

extern "C" void kernel_launch(void* const* d_in, const int* in_sizes, int n_in,
                              void* d_out, int out_size, void* d_ws, size_t ws_size,
                              hipStream_t stream) {
    const float* X      = (const float*)d_in[0];
    const float* target = (const float*)d_in[1];
    const float* params = (const float*)d_in[2];
    float* out = (float*)d_out;

    float* ws = (float*)d_ws;
    float2* partial = (float2*)ws;                 // 2080 float2 (16.6 KB)
    float* Lsq = ws + 8192;                        // 8192 floats (32 KB)
    short* Xp  = (short*)(ws + 16384);             // panelized bf16, 1 MB, 64KB-offset aligned

    prep_kernel<<<NROWS / 32, 256, 0, stream>>>(X, params, Lsq, Xp);
    kta_main<<<NTRI, 256, 0, stream>>>(Xp, Lsq, target, partial);
    finalize_kernel<<<1, 256, 0, stream>>>(partial, out);
}

// Round 9
// 75.154 us; speedup vs baseline: 1.0860x; 1.0141x over previous
//
#include <hip/hip_runtime.h>
#include <hip/hip_bf16.h>

#define NROWS 8192
#define DIM 64
#define NT 64                     // 64x64 grid of 128x128 tiles
#define NTRI (NT * (NT + 1) / 2)  // 2080 upper-triangle tiles

typedef __attribute__((ext_vector_type(8))) short short8;   // 8 bf16 = 4 VGPRs
typedef __attribute__((ext_vector_type(4))) float f32x4;    // MFMA 16x16 accumulator

static constexpr float LOG2E = 1.4426950408889634f;

#if defined(__has_builtin) && __has_builtin(__builtin_amdgcn_exp2f)
#define EXP2F(x) __builtin_amdgcn_exp2f(x)
#else
#define EXP2F(x) exp2f(x)
#endif

// Panelized bf16 layout: panel p = row/16 holds rows 16p..16p+15.
// Within a panel, 8 k-chunks (c = k/8), stored chunk-major in 16B units:
//   unit_index = p*128 + c*16 + (row%16)
// An MFMA A/B fragment load (lane l16 = row%16, quad = (k/8)%4) is then a
// fully-coalesced contiguous 1KB wave load — no cache-line splits.
//
// Session ledger (8 rounds of A/B on MI355X):
//  - fused finalize via device fence+atomic per block: +26 us (r1-2). NEVER.
//  - prep fused into kta (per-block re-conversion): +7 us (r6).
//  - cooperative single-kernel w/ grid.sync: incorrect under harness (r8).
//  - occupancy/prefetch/TPB/LDS-staging/nt-stores: all neutral (r2-5,7).
// This is the proven-best round-3 configuration: 3 kernels, all-live
// fragments in kta (max in-wave ILP), epilogue operands prefetched before
// the MFMA cluster, plain stores.
__global__ __launch_bounds__(256) void prep_kernel(const float* __restrict__ X,
                                                   const float* __restrict__ params,
                                                   float* __restrict__ Lsq,
                                                   short* __restrict__ Xp) {
    int tid  = threadIdx.x;
    int wave = tid >> 6, lane = tid & 63;
    int r8 = lane >> 3, c = lane & 7;        // 8 rows x 8 chunks per wave
    int row = blockIdx.x * 32 + wave * 8 + r8;

    const float* xr = X + row * DIM + c * 8;
    float4 x0 = *(const float4*)xr;
    float4 x1 = *(const float4*)(xr + 4);
    float4 p0 = *(const float4*)(params + c * 8);
    float4 p1 = *(const float4*)(params + c * 8 + 4);

    float v[8];
    v[0] = x0.x * sqrtf(p0.x); v[1] = x0.y * sqrtf(p0.y);
    v[2] = x0.z * sqrtf(p0.z); v[3] = x0.w * sqrtf(p0.w);
    v[4] = x1.x * sqrtf(p1.x); v[5] = x1.y * sqrtf(p1.y);
    v[6] = x1.z * sqrtf(p1.z); v[7] = x1.w * sqrtf(p1.w);

    short8 h;
    float s = 0.f;
    #pragma unroll
    for (int i = 0; i < 8; ++i) {
        __hip_bfloat16 b = __float2bfloat16(v[i]);
        union { __hip_bfloat16 bb; short ss; } u; u.bb = b;
        h[i] = u.ss;
        float bf = __bfloat162float(b);   // rounded value, consistent with MFMA dot
        s += bf * bf;
    }

    int panel = row >> 4, pr = row & 15;
    ((short8*)Xp)[panel * 128 + c * 16 + pr] = h;

    // sum s over the 8 chunk-lanes of this row (xor over lane bits 0..2)
    #pragma unroll
    for (int m = 1; m < 8; m <<= 1) s += __shfl_xor(s, m, 64);
    if (c == 0) Lsq[row] = LOG2E * s;
}

// Main: compact upper-triangle grid of 128x128 tiles; each of 4 waves computes
// a 64x64 subtile via 16x16x32 bf16 MFMA from the panelized layout, then a
// fused exp epilogue. All fragments + all 16 acc tiles live (max in-wave ILP);
// epilogue operands prefetched BEFORE the MFMA cluster so their L2 latency
// hides under the MFMAs.
__global__ __launch_bounds__(256, 2) void kta_main(const short* __restrict__ Xp,
                                                   const float* __restrict__ Lsq,
                                                   const float* __restrict__ t,
                                                   float2* __restrict__ partial) {
    int k = blockIdx.x;
    // decode triangular index: row it has tiles jt = it..NT-1; C(i)=i*(129-i)/2
    int it = (int)((129.0f - sqrtf(16641.0f - 8.0f * (float)k)) * 0.5f);
    if (it > NT - 1) it = NT - 1;
    while ((it * (129 - it)) / 2 > k) --it;
    while (((it + 1) * (128 - it)) / 2 <= k) ++it;
    int jt = it + (k - (it * (129 - it)) / 2);

    int tid  = threadIdx.x;
    int wave = tid >> 6, lane = tid & 63;
    int quad = lane >> 4, l16 = lane & 15;
    int rbase = it * 128 + (wave >> 1) * 64;
    int cbase = jt * 128 + (wave & 1) * 64;

    // Coalesced fragment loads from panelized Xs.
    // A-operand (16x16x32 bf16): lane holds A[m=l16][k=quad*8+j]; B symmetric.
    const short8* Xpv = (const short8*)Xp;
    int pA0 = rbase >> 4, pB0 = cbase >> 4;
    short8 afr[4][2], bfr[4][2];
    #pragma unroll
    for (int rt = 0; rt < 4; ++rt) {
        #pragma unroll
        for (int kc = 0; kc < 2; ++kc) {
            afr[rt][kc] = Xpv[(pA0 + rt) * 128 + (kc * 4 + quad) * 16 + l16];
            bfr[rt][kc] = Xpv[(pB0 + rt) * 128 + (kc * 4 + quad) * 16 + l16];
        }
    }

    // Prefetch ALL epilogue operands before the MFMA cluster: their L2
    // latency overlaps the 32-MFMA stream instead of stalling the epilogue.
    float LsqR[4][4], tR[4][4];
    #pragma unroll
    for (int rt = 0; rt < 4; ++rt)
        #pragma unroll
        for (int r = 0; r < 4; ++r) {
            int row = rbase + rt * 16 + quad * 4 + r;
            LsqR[rt][r] = Lsq[row];
            tR[rt][r]   = t[row];
        }
    float LsqC[4], tC[4];
    #pragma unroll
    for (int ct = 0; ct < 4; ++ct) {
        int col = cbase + ct * 16 + l16;
        LsqC[ct] = Lsq[col];
        tC[ct]   = t[col];
    }

    f32x4 c[4][4];
    #pragma unroll
    for (int rt = 0; rt < 4; ++rt)
        #pragma unroll
        for (int ct = 0; ct < 4; ++ct)
            c[rt][ct] = (f32x4){0.f, 0.f, 0.f, 0.f};

    #pragma unroll
    for (int rt = 0; rt < 4; ++rt)
        #pragma unroll
        for (int ct = 0; ct < 4; ++ct) {
            c[rt][ct] = __builtin_amdgcn_mfma_f32_16x16x32_bf16(afr[rt][0], bfr[ct][0], c[rt][ct], 0, 0, 0);
            c[rt][ct] = __builtin_amdgcn_mfma_f32_16x16x32_bf16(afr[rt][1], bfr[ct][1], c[rt][ct], 0, 0, 0);
        }

    bool diagwave = (it == jt) && ((wave >> 1) == (wave & 1));

    float s1 = 0.f, s2a = 0.f, s2b = 0.f;

    // DIAG is a call-site literal; clang inlines + const-folds both versions,
    // so non-diag waves (the vast majority) carry zero diagonal-compare cost.
    auto run = [&](int DIAG) {
        #pragma unroll
        for (int rt = 0; rt < 4; ++rt) {
            // Epilogue. C/D layout: col = lane&15, row = quad*4 + reg.
            #pragma unroll
            for (int r = 0; r < 4; ++r) {
                float nr = LsqR[rt][r];
                float s1row = 0.f;
                #pragma unroll
                for (int ct = 0; ct < 4; ++ct) {
                    float dot = c[rt][ct][r];
                    // off-diag d2 >= ~15 for this data: no clamp needed; diagonal
                    // (the only d2~0 entries) is pinned to 1 below.
                    float K = EXP2F(fmaf(dot, 2.0f * LOG2E, -(nr + LsqC[ct])));
                    // diag wave => rbase==cbase, so row==col iff rt==ct && quad*4+r==l16
                    if (DIAG && (rt == ct) && ((quad * 4 + r) == l16))
                        K = 1.0f;
                    s1row = fmaf(K, tC[ct], s1row);
                    if (ct & 2) s2b = fmaf(K, K, s2b);
                    else        s2a = fmaf(K, K, s2a);
                }
                s1 = fmaf(s1row, tR[rt][r], s1);
            }
        }
    };
    if (diagwave) run(1); else run(0);

    float s2 = s2a + s2b;
    float w = (it == jt) ? 1.0f : 2.0f;
    s1 *= w; s2 *= w;
    #pragma unroll
    for (int m = 32; m > 0; m >>= 1) {
        s1 += __shfl_xor(s1, m, 64);
        s2 += __shfl_xor(s2, m, 64);
    }

    __shared__ float2 red[4];
    if (lane == 0) red[wave] = make_float2(s1, s2);
    __syncthreads();
    if (tid == 0) {
        float2 a = red[0], b = red[1], cc = red[2], d = red[3];
        partial[k] = make_float2(a.x + b.x + cc.x + d.x, a.y + b.y + cc.y + d.y);
    }
}

// Single-block reduction of per-block partials (2080 float2 = 16.6 KB).
__global__ __launch_bounds__(256) void finalize_kernel(const float2* __restrict__ partial,
                                                       float* __restrict__ out) {
    float s1 = 0.f, s2 = 0.f;
    for (int i = threadIdx.x; i < NTRI; i += 256) {
        float2 p = partial[i];
        s1 += p.x;
        s2 += p.y;
    }
    #pragma unroll
    for (int m = 32; m > 0; m >>= 1) {
        s1 += __shfl_xor(s1, m, 64);
        s2 += __shfl_xor(s2, m, 64);
    }
    __shared__ float r1[4], r2[4];
    int wave = threadIdx.x >> 6, lane = threadIdx.x & 63;
    if (lane == 0) { r1[wave] = s1; r2[wave] = s2; }
    __syncthreads();
    if (threadIdx.x == 0) {
        float a = r1[0] + r1[1] + r1[2] + r1[3];
        float b = r2[0] + r2[1] + r2[2] + r2[3];
        out[0] = -a / ((float)NROWS * sqrtf(b));
    }
}

extern "C" void kernel_launch(void* const* d_in, const int* in_sizes, int n_in,
                              void* d_out, int out_size, void* d_ws, size_t ws_size,
                              hipStream_t stream) {
    const float* X      = (const float*)d_in[0];
    const float* target = (const float*)d_in[1];
    const float* params = (const float*)d_in[2];
    float* out = (float*)d_out;

    float* ws = (float*)d_ws;
    float2* partial = (float2*)ws;                 // 2080 float2 (16.6 KB)
    float* Lsq = ws + 8192;                        // 8192 floats (32 KB)
    short* Xp  = (short*)(ws + 16384);             // panelized bf16, 1 MB, 64KB-offset aligned

    prep_kernel<<<NROWS / 32, 256, 0, stream>>>(X, params, Lsq, Xp);
    kta_main<<<NTRI, 256, 0, stream>>>(Xp, Lsq, target, partial);
    finalize_kernel<<<1, 256, 0, stream>>>(partial, out);
}